// Round 12
// baseline (497.748 us; speedup 1.0000x reference)
//
#include <hip/hip_runtime.h>
#include <hip/hip_bf16.h>
#include <math.h>

typedef __attribute__((ext_vector_type(8))) short bf16x8;
typedef __attribute__((ext_vector_type(4))) float f32x4;

__device__ inline unsigned short f2bf(float f) {
    return __builtin_bit_cast(unsigned short, __float2bfloat16(f));
}
__device__ inline float bf2f(unsigned short u) {
    return __bfloat162float(__builtin_bit_cast(__hip_bfloat16, u));
}
__device__ inline bf16x8 cvt8(float4 a, float4 b) {
    bf16x8 r;
    r[0]=(short)f2bf(a.x); r[1]=(short)f2bf(a.y); r[2]=(short)f2bf(a.z); r[3]=(short)f2bf(a.w);
    r[4]=(short)f2bf(b.x); r[5]=(short)f2bf(b.y); r[6]=(short)f2bf(b.z); r[7]=(short)f2bf(b.w);
    return r;
}
__device__ inline void split8(float4 a, float4 b, bf16x8& hi, bf16x8& lo) {
    float f[8] = {a.x,a.y,a.z,a.w,b.x,b.y,b.z,b.w};
    #pragma unroll
    for (int i = 0; i < 8; ++i) {
        unsigned short h = f2bf(f[i]);
        hi[i] = (short)h;
        lo[i] = (short)f2bf(f[i] - bf2f(h));
    }
}

// LDS map (float-index units; total 4528 fl = 18112 B -> 8 blocks/CU = 32 waves/CU):
//  xv   f32 [25][65]     @0      whole kernel (stride 65: conflict-free)
//  ynh  u16 [25][64]swz  @1628   P1->P2 (qk frag rows>=25 spill into ynl: garbage, discarded)
//  ynl  u16 [25][64]swz  @2428   P1->P2 (spill into qkb: garbage, discarded)
//  A_bf u16 [80][40]     @1628   P3->P4 (overlays yn exactly; rows 75-79 never written, discarded)
//  zA   u16 [25][200]    @1628   P4b->P5 (overlays A_bf after drain barrier; ends @4128)
//  qkb  f32 [25][52]     @3228   P2->P3
#define LDS_FLOATS 4528

__global__ __launch_bounds__(256, 8)
void agcn_fused_kernel(const float* __restrict__ x,
                       const float* __restrict__ PA,
                       const float* __restrict__ ln_g, const float* __restrict__ ln_b,
                       const float* __restrict__ Wqk, const float* __restrict__ bqk,
                       const float* __restrict__ conv_w, const float* __restrict__ conv_b,
                       const float* __restrict__ bn_g, const float* __restrict__ bn_b,
                       const float* __restrict__ bn_m, const float* __restrict__ bn_v,
                       float* __restrict__ out)
{
    __shared__ float lds[LDS_FLOATS];
    float* xv = lds;                                      // [25][65]
    unsigned short* ynh  = (unsigned short*)(lds + 1628);
    unsigned short* ynl  = (unsigned short*)(lds + 2428);
    unsigned short* A_bf = (unsigned short*)(lds + 1628); // [80][40]
    unsigned short* zA   = (unsigned short*)(lds + 1628); // [25][200]
    float* qkb = lds + 3228;                              // [25][52]

    const int bid = blockIdx.x;
    const int n = bid >> 7, t = bid & 127;
    const int tid = threadIdx.x;
    const int lane = tid & 63, w = tid >> 6;
    const int g = lane >> 4, l15 = lane & 15;
    const int o = 16 * w + l15;

    // ============ prologue: issue all param loads ============
    float4 cw_f[12];
    #pragma unroll
    for (int kt = 0; kt < 6; ++kt) {
        const float* wp = &conv_w[(kt >> 1) * 4096 + o * 64 + (kt & 1) * 32 + 8 * g];
        cw_f[2*kt]   = *(const float4*)wp;
        cw_f[2*kt+1] = *(const float4*)(wp + 4);
    }
    float4 wq_f[4];
    float bq = 0.f;
    if (w < 3) {
        const int j = 16 * w + l15;
        #pragma unroll
        for (int ks = 0; ks < 2; ++ks) {
            const float* wp = &Wqk[j * 64 + ks * 32 + 8 * g];
            wq_f[2*ks]   = *(const float4*)wp;
            wq_f[2*ks+1] = *(const float4*)(wp + 4);
        }
        bq = bqk[j];
    }
    // per-lane LN params (8 columns owned in P1)
    const int c0 = (lane & 7) << 3;
    const float4 lg0 = *(const float4*)&ln_g[c0];
    const float4 lg1 = *(const float4*)&ln_g[c0 + 4];
    const float4 lb0 = *(const float4*)&ln_b[c0];
    const float4 lb1 = *(const float4*)&ln_b[c0 + 4];
    const float sc_e = bn_g[o] * rsqrtf(bn_v[o] + 1e-5f);
    const float bi_e = (conv_b[o] + conv_b[64 + o] + conv_b[128 + o]) * sc_e
                       + bn_b[o] - bn_m[o] * sc_e;

    // ---- P0: stage x tile ----
    {
        const float* xb = x + (size_t)n * 204800 + t * 25;
        for (int idx = tid; idx < 1600; idx += 256) {
            int c = idx / 25, v = idx - c * 25;
            xv[v * 65 + c] = xb[c * 3200 + v];
        }
    }

    bf16x8 cw[6];
    #pragma unroll
    for (int kt = 0; kt < 6; ++kt) cw[kt] = cvt8(cw_f[2*kt], cw_f[2*kt+1]);
    bf16x8 wqh[2], wql[2];
    if (w < 3) {
        #pragma unroll
        for (int ks = 0; ks < 2; ++ks) split8(wq_f[2*ks], wq_f[2*ks+1], wqh[ks], wql[ks]);
    }
    __syncthreads();

    // ---- P1: one-pass LN, 8-lane group per row (all 25 rows in parallel) ----
    {
        const int vr = (w << 3) + (lane >> 3);
        if (vr < 25) {
            float xa[8];
            #pragma unroll
            for (int i = 0; i < 8; ++i) xa[i] = xv[vr * 65 + c0 + i];
            float s1 = ((xa[0]+xa[1])+(xa[2]+xa[3])) + ((xa[4]+xa[5])+(xa[6]+xa[7]));
            float s2 = ((xa[0]*xa[0]+xa[1]*xa[1])+(xa[2]*xa[2]+xa[3]*xa[3]))
                     + ((xa[4]*xa[4]+xa[5]*xa[5])+(xa[6]*xa[6]+xa[7]*xa[7]));
            s1 += __shfl_xor(s1, 1);  s2 += __shfl_xor(s2, 1);
            s1 += __shfl_xor(s1, 2);  s2 += __shfl_xor(s2, 2);
            s1 += __shfl_xor(s1, 4);  s2 += __shfl_xor(s2, 4);
            float mu = s1 * (1.0f / 64.0f);
            float var = s2 * (1.0f / 64.0f) - mu * mu;
            float rstd = rsqrtf(var + 1e-5f);
            float lg[8] = {lg0.x,lg0.y,lg0.z,lg0.w,lg1.x,lg1.y,lg1.z,lg1.w};
            float lb[8] = {lb0.x,lb0.y,lb0.z,lb0.w,lb1.x,lb1.y,lb1.z,lb1.w};
            bf16x8 hh8, ll8;
            #pragma unroll
            for (int i = 0; i < 8; ++i) {
                float y = (xa[i] - mu) * rstd * lg[i] + lb[i];
                unsigned short hh = f2bf(y);
                hh8[i] = (short)hh;
                ll8[i] = (short)f2bf(y - bf2f(hh));
            }
            int base = (vr * 64 + c0) ^ ((vr & 7) << 3);
            *(bf16x8*)&ynh[base] = hh8;
            *(bf16x8*)&ynl[base] = ll8;
        }
    }
    __syncthreads();

    // ---- P2: qk MFMA (waves 0-2) -> qkb f32 ----
    if (w < 3) {
        const int j = 16 * w + l15;
        #pragma unroll
        for (int mt = 0; mt < 2; ++mt) {
            f32x4 acc = {bq, bq, bq, bq};
            #pragma unroll
            for (int ks = 0; ks < 2; ++ks) {
                int row = 16 * mt + l15;
                int idx = (row * 64 + ks * 32 + 8 * g) ^ ((row & 7) << 3);
                bf16x8 ah = *(bf16x8*)&ynh[idx];
                bf16x8 al = *(bf16x8*)&ynl[idx];
                acc = __builtin_amdgcn_mfma_f32_16x16x32_bf16(al, wqh[ks], acc, 0, 0, 0);
                acc = __builtin_amdgcn_mfma_f32_16x16x32_bf16(ah, wql[ks], acc, 0, 0, 0);
                acc = __builtin_amdgcn_mfma_f32_16x16x32_bf16(ah, wqh[ks], acc, 0, 0, 0);
            }
            #pragma unroll
            for (int reg = 0; reg < 4; ++reg) {
                int v = 16 * mt + 4 * g + reg;
                if (v < 25) qkb[v * 52 + j] = acc[reg];
            }
        }
    }
    __syncthreads();

    // ---- P3: FUSED dots + softmax*PA (2 threads per row) -> A_bf ----
    if (tid < 150) {
        int r = tid >> 1, hf = tid & 1;
        int h = (r < 25) ? 0 : ((r < 50) ? 1 : 2);
        int i = r - h * 25;
        const float4* qp = (const float4*)&qkb[i * 52 + h * 8];
        float4 q0 = qp[0], q1 = qp[1];
        const int j0 = hf ? 13 : 0;
        const int cnt = hf ? 12 : 13;
        const float* pa = &PA[h * 625 + i * 25];
        float rr[13];
        #pragma unroll
        for (int jj = 0; jj < 13; ++jj) {
            int j = j0 + jj;
            int jc = (j < 25) ? j : 0;
            const float4* kp = (const float4*)&qkb[jc * 52 + 24 + h * 8];
            float4 k0 = kp[0], k1 = kp[1];
            float d = q0.x*k0.x + q0.y*k0.y + q0.z*k0.z + q0.w*k0.w
                    + q1.x*k1.x + q1.y*k1.y + q1.z*k1.z + q1.w*k1.w;
            rr[jj] = (jj < cnt) ? d * 0.35355339059327373f : -3.0e38f;
        }
        float m0 = fmaxf(rr[0], rr[1]),  m1 = fmaxf(rr[2], rr[3]);
        float m2 = fmaxf(rr[4], rr[5]),  m3 = fmaxf(rr[6], rr[7]);
        float m4 = fmaxf(rr[8], rr[9]),  m5 = fmaxf(rr[10], rr[11]);
        float m = fmaxf(fmaxf(fmaxf(m0, m1), fmaxf(m2, m3)),
                        fmaxf(fmaxf(m4, m5), rr[12]));
        m = fmaxf(m, __shfl_xor(m, 1));
        float s = 0.f;
        #pragma unroll
        for (int jj = 0; jj < 13; ++jj) {
            rr[jj] = __expf(rr[jj] - m);     // pad lanes: exp(-inf) = 0
            s += rr[jj];
        }
        s += __shfl_xor(s, 1);
        float inv = 1.0f / s;
        unsigned short* ar = &A_bf[r * 40];
        #pragma unroll
        for (int jj = 0; jj < 13; ++jj) {
            int j = j0 + jj;
            if (jj < cnt) ar[j] = f2bf(rr[jj] * inv * pa[j]);
        }
        if (hf) {
            #pragma unroll
            for (int j = 25; j < 32; ++j) ar[j] = 0;
        }
    }
    __syncthreads();

    // ---- P4: z MFMA (B-frag direct from xv) -> regs; deferred zA write ----
    f32x4 zacc[5];
    {
        bf16x8 bfrag;
        #pragma unroll
        for (int i = 0; i < 8; ++i) {
            int j = 8 * g + i;
            bfrag[i] = (j < 25) ? (short)f2bf(xv[j * 65 + o]) : (short)0;
        }
        #pragma unroll
        for (int mt = 0; mt < 5; ++mt) {
            bf16x8 afrag = *(bf16x8*)&A_bf[(16 * mt + l15) * 40 + 8 * g];
            f32x4 a = {0.f, 0.f, 0.f, 0.f};
            zacc[mt] = __builtin_amdgcn_mfma_f32_16x16x32_bf16(afrag, bfrag, a, 0, 0, 0);
        }
    }
    __syncthreads();   // A_bf frag reads drained; region free for zA

    #pragma unroll
    for (int mt = 0; mt < 5; ++mt) {
        #pragma unroll
        for (int reg = 0; reg < 4; ++reg) {
            int r = 16 * mt + 4 * g + reg;
            if (r < 75) {
                int h = (r < 25) ? 0 : ((r < 50) ? 1 : 2);
                int i = r - h * 25;
                zA[i * 200 + h * 64 + 16 * w + l15] = f2bf(zacc[mt][reg]);
            }
        }
    }
    __syncthreads();

    // ---- P5: conv MFMA + BN + residual + ReLU + direct store ----
    {
        const int r1 = (16 + l15 < 25) ? (16 + l15) : 0;
        f32x4 acc0 = {0.f, 0.f, 0.f, 0.f}, acc1 = {0.f, 0.f, 0.f, 0.f};
        #pragma unroll
        for (int kt = 0; kt < 6; ++kt) {
            bf16x8 a0 = *(bf16x8*)&zA[l15 * 200 + 32 * kt + 8 * g];
            bf16x8 a1 = *(bf16x8*)&zA[r1 * 200 + 32 * kt + 8 * g];
            acc0 = __builtin_amdgcn_mfma_f32_16x16x32_bf16(a0, cw[kt], acc0, 0, 0, 0);
            acc1 = __builtin_amdgcn_mfma_f32_16x16x32_bf16(a1, cw[kt], acc1, 0, 0, 0);
        }
        float* ob = out + (size_t)n * 204800 + (size_t)o * 3200 + t * 25;
        #pragma unroll
        for (int reg = 0; reg < 4; ++reg) {
            int v = 4 * g + reg;
            float val = acc0[reg] * sc_e + bi_e + xv[v * 65 + o];
            ob[v] = fmaxf(val, 0.f);
        }
        #pragma unroll
        for (int reg = 0; reg < 4; ++reg) {
            int v = 16 + 4 * g + reg;
            if (v < 25) {
                float val = acc1[reg] * sc_e + bi_e + xv[v * 65 + o];
                ob[v] = fmaxf(val, 0.f);
            }
        }
    }
}

extern "C" void kernel_launch(void* const* d_in, const int* in_sizes, int n_in,
                              void* d_out, int out_size, void* d_ws, size_t ws_size,
                              hipStream_t stream) {
    const float* x      = (const float*)d_in[0];
    const float* PA     = (const float*)d_in[1];
    const float* ln_g   = (const float*)d_in[2];
    const float* ln_b   = (const float*)d_in[3];
    const float* Wqk    = (const float*)d_in[4];
    const float* bqk    = (const float*)d_in[5];
    const float* conv_w = (const float*)d_in[6];
    const float* conv_b = (const float*)d_in[7];
    const float* bn_g   = (const float*)d_in[8];
    const float* bn_b   = (const float*)d_in[9];
    const float* bn_m   = (const float*)d_in[10];
    const float* bn_v   = (const float*)d_in[11];
    float* outp = (float*)d_out;

    agcn_fused_kernel<<<dim3(128 * 128), dim3(256), 0, stream>>>(
        x, PA, ln_g, ln_b, Wqk, bqk, conv_w, conv_b,
        bn_g, bn_b, bn_m, bn_v, outp);
}

// Round 13
// 297.426 us; speedup vs baseline: 1.6735x; 1.6735x over previous
//
#include <hip/hip_runtime.h>
#include <hip/hip_bf16.h>
#include <math.h>

typedef __attribute__((ext_vector_type(8))) short bf16x8;
typedef __attribute__((ext_vector_type(4))) float f32x4;

__device__ inline unsigned short f2bf(float f) {
    return __builtin_bit_cast(unsigned short, __float2bfloat16(f));
}
__device__ inline float bf2f(unsigned short u) {
    return __bfloat162float(__builtin_bit_cast(__hip_bfloat16, u));
}
__device__ inline bf16x8 cvt8(float4 a, float4 b) {
    bf16x8 r;
    r[0]=(short)f2bf(a.x); r[1]=(short)f2bf(a.y); r[2]=(short)f2bf(a.z); r[3]=(short)f2bf(a.w);
    r[4]=(short)f2bf(b.x); r[5]=(short)f2bf(b.y); r[6]=(short)f2bf(b.z); r[7]=(short)f2bf(b.w);
    return r;
}
__device__ inline void split8(float4 a, float4 b, bf16x8& hi, bf16x8& lo) {
    float f[8] = {a.x,a.y,a.z,a.w,b.x,b.y,b.z,b.w};
    #pragma unroll
    for (int i = 0; i < 8; ++i) {
        unsigned short h = f2bf(f[i]);
        hi[i] = (short)h;
        lo[i] = (short)f2bf(f[i] - bf2f(h));
    }
}

// LDS map (float idx units; total 6403 fl = 25612 B -> 6 blocks/CU)  [R5-identical]:
//  xv   f32 [25][65]          @0      p0..end
//  ynh  u16 logical[32][64]sw @1628   p1-2 (rows>=25 spill-read: garbage, discarded)
//  ynl  u16 logical[32][64]sw @2428   p1-2
//  A_bf u16 [80][40]          @1628   p4-5 (overlays ynh+ynl exactly, 6400 B)
//  qkb  f32 [25][52]          @3228   p2-3
//  xvT  u16 [64][40]          @3228   p4-5 (overlays qkb, 5120 B)
//  Abuf f32 [75][25]          @4528   p3-4
//  zA   u16 [25][200]         @1628   p6   (written after p5 drains, overlays A_bf+xvT)
//  res  f32 [64][25]          @4528   epilogue (overlays dead Abuf; disjoint from zA)
#define LDS_FLOATS 6403

__global__ __launch_bounds__(256, 6)
void agcn_fused_kernel(const float* __restrict__ x,
                       const float* __restrict__ PA,
                       const float* __restrict__ ln_g, const float* __restrict__ ln_b,
                       const float* __restrict__ Wqk, const float* __restrict__ bqk,
                       const float* __restrict__ conv_w, const float* __restrict__ conv_b,
                       const float* __restrict__ bn_g, const float* __restrict__ bn_b,
                       const float* __restrict__ bn_m, const float* __restrict__ bn_v,
                       float* __restrict__ out)
{
    __shared__ float lds[LDS_FLOATS];
    float* xv = lds;                                        // [25][65]
    unsigned short* ynh = (unsigned short*)(lds + 1628);
    unsigned short* ynl = (unsigned short*)(lds + 2428);
    unsigned short* A_bf = (unsigned short*)(lds + 1628);   // [80][40]
    float* qkb  = lds + 3228;                               // [25][52]
    unsigned short* xvT = (unsigned short*)(lds + 3228);    // [64][40]
    float* Abuf = lds + 4528;                               // [75][25]
    unsigned short* zA  = (unsigned short*)(lds + 1628);    // [25][200]
    float* res  = lds + 4528;                               // [64][25]

    const int bid = blockIdx.x;
    const int n = bid >> 7, t = bid & 127;
    const int tid = threadIdx.x;
    const int lane = tid & 63, w = tid >> 6;
    const int g = lane >> 4, l15 = lane & 15;

    // ================= prologue: issue ALL weight loads =================
    const int o = 16 * w + l15;
    float4 cw_f[12];
    #pragma unroll
    for (int kt = 0; kt < 6; ++kt) {
        const float* wp = &conv_w[(kt >> 1) * 4096 + o * 64 + (kt & 1) * 32 + 8 * g];
        cw_f[2*kt]   = *(const float4*)wp;
        cw_f[2*kt+1] = *(const float4*)(wp + 4);
    }
    float4 wq_f[4];
    float bq = 0.f;
    if (w < 3) {
        const int j = 16 * w + l15;
        #pragma unroll
        for (int ks = 0; ks < 2; ++ks) {
            const float* wp = &Wqk[j * 64 + ks * 32 + 8 * g];
            wq_f[2*ks]   = *(const float4*)wp;
            wq_f[2*ks+1] = *(const float4*)(wp + 4);
        }
        bq = bqk[j];
    }
    // per-lane LN params for the 8 columns owned in P1
    const int c0 = (lane & 7) << 3;
    const float4 lg0 = *(const float4*)&ln_g[c0];
    const float4 lg1 = *(const float4*)&ln_g[c0 + 4];
    const float4 lb0 = *(const float4*)&ln_b[c0];
    const float4 lb1 = *(const float4*)&ln_b[c0 + 4];

    // ---- phase 0: stage x tile ----
    const float* xbase = x + (size_t)n * 204800 + t * 25;
    for (int idx = tid; idx < 1600; idx += 256) {
        int c = idx / 25, v = idx - c * 25;
        xv[v * 65 + c] = xbase[c * 3200 + v];
    }

    bf16x8 cw[6];
    #pragma unroll
    for (int kt = 0; kt < 6; ++kt) cw[kt] = cvt8(cw_f[2*kt], cw_f[2*kt+1]);
    bf16x8 wqh[2], wql[2];
    if (w < 3) {
        #pragma unroll
        for (int ks = 0; ks < 2; ++ks) split8(wq_f[2*ks], wq_f[2*ks+1], wqh[ks], wql[ks]);
    }
    __syncthreads();

    // ---- phase 1: one-pass parallel LN (8 lanes per row, all 25 rows at once) ----
    {
        const int vr = (w << 3) + (lane >> 3);     // 0..31
        if (vr < 25) {
            float xa[8];
            #pragma unroll
            for (int i = 0; i < 8; ++i) xa[i] = xv[vr * 65 + c0 + i];
            float s1 = ((xa[0]+xa[1])+(xa[2]+xa[3])) + ((xa[4]+xa[5])+(xa[6]+xa[7]));
            float s2 = ((xa[0]*xa[0]+xa[1]*xa[1])+(xa[2]*xa[2]+xa[3]*xa[3]))
                     + ((xa[4]*xa[4]+xa[5]*xa[5])+(xa[6]*xa[6]+xa[7]*xa[7]));
            s1 += __shfl_xor(s1, 1);  s2 += __shfl_xor(s2, 1);
            s1 += __shfl_xor(s1, 2);  s2 += __shfl_xor(s2, 2);
            s1 += __shfl_xor(s1, 4);  s2 += __shfl_xor(s2, 4);
            float mu = s1 * (1.0f / 64.0f);
            float var = s2 * (1.0f / 64.0f) - mu * mu;
            float rstd = rsqrtf(var + 1e-5f);
            float lg[8] = {lg0.x,lg0.y,lg0.z,lg0.w,lg1.x,lg1.y,lg1.z,lg1.w};
            float lb[8] = {lb0.x,lb0.y,lb0.z,lb0.w,lb1.x,lb1.y,lb1.z,lb1.w};
            bf16x8 hh8, ll8;
            #pragma unroll
            for (int i = 0; i < 8; ++i) {
                float y = (xa[i] - mu) * rstd * lg[i] + lb[i];
                unsigned short hh = f2bf(y);
                hh8[i] = (short)hh;
                ll8[i] = (short)f2bf(y - bf2f(hh));
            }
            int base = (vr * 64 + c0) ^ ((vr & 7) << 3);
            *(bf16x8*)&ynh[base] = hh8;
            *(bf16x8*)&ynl[base] = ll8;
        }
    }
    __syncthreads();

    // ---- phase 2: qk MFMA (waves 0-2): qkb[v][j], 3-term hi/lo ----
    if (w < 3) {
        const int j = 16 * w + l15;
        #pragma unroll
        for (int mt = 0; mt < 2; ++mt) {
            f32x4 acc = {bq, bq, bq, bq};
            #pragma unroll
            for (int ks = 0; ks < 2; ++ks) {
                int row = 16 * mt + l15;
                int idx = (row * 64 + ks * 32 + 8 * g) ^ ((row & 7) << 3);
                bf16x8 ah = *(bf16x8*)&ynh[idx];
                bf16x8 al = *(bf16x8*)&ynl[idx];
                acc = __builtin_amdgcn_mfma_f32_16x16x32_bf16(al, wqh[ks], acc, 0, 0, 0);
                acc = __builtin_amdgcn_mfma_f32_16x16x32_bf16(ah, wql[ks], acc, 0, 0, 0);
                acc = __builtin_amdgcn_mfma_f32_16x16x32_bf16(ah, wqh[ks], acc, 0, 0, 0);
            }
            #pragma unroll
            for (int reg = 0; reg < 4; ++reg) {
                int v = 16 * mt + 4 * g + reg;
                if (v < 25) qkb[v * 52 + j] = acc[reg];
            }
        }
    }
    __syncthreads();

    // ---- phase 3: dots (fp32 VALU) ----
    for (int idx = tid; idx < 1875; idx += 256) {
        int h = idx / 625, r = idx - h * 625;
        int i = r / 25, j = r - i * 25;
        const float4* q = (const float4*)&qkb[i * 52 + h * 8];
        const float4* k = (const float4*)&qkb[j * 52 + 24 + h * 8];
        float4 q0 = q[0], q1 = q[1], k0 = k[0], k1 = k[1];
        float d = q0.x*k0.x + q0.y*k0.y + q0.z*k0.z + q0.w*k0.w
                + q1.x*k1.x + q1.y*k1.y + q1.z*k1.z + q1.w*k1.w;
        Abuf[idx] = d * 0.35355339059327373f;
    }
    __syncthreads();

    // ---- phase 4: softmax*PA -> A_bf ; xv -> xvT ----
    if (tid < 75) {
        int h = tid / 25, i = tid - h * 25;
        const float* row = &Abuf[h * 625 + i * 25];
        const float* pa = &PA[h * 625 + i * 25];
        float m = row[0];
        #pragma unroll
        for (int j = 1; j < 25; ++j) m = fmaxf(m, row[j]);
        float e[25];
        float s = 0.f;
        #pragma unroll
        for (int j = 0; j < 25; ++j) { e[j] = __expf(row[j] - m); s += e[j]; }
        float inv = 1.0f / s;
        unsigned short* ar = &A_bf[(h * 25 + i) * 40];
        #pragma unroll
        for (int j = 0; j < 25; ++j) ar[j] = f2bf(e[j] * inv * pa[j]);
        #pragma unroll
        for (int j = 25; j < 32; ++j) ar[j] = 0;
    }
    for (int idx = tid; idx < 2560; idx += 256) {
        int c = idx / 40, j = idx - c * 40;
        float val = (j < 25) ? xv[j * 65 + c] : 0.f;
        xvT[idx] = f2bf(val);
    }
    __syncthreads();

    // ---- phase 5: z MFMA -> registers (zA write deferred past barrier) ----
    f32x4 zacc[5];
    {
        bf16x8 bfrag = *(bf16x8*)&xvT[(16 * w + l15) * 40 + 8 * g];
        #pragma unroll
        for (int mt = 0; mt < 5; ++mt) {
            bf16x8 afrag = *(bf16x8*)&A_bf[(16 * mt + l15) * 40 + 8 * g];
            f32x4 a = {0.f, 0.f, 0.f, 0.f};
            zacc[mt] = __builtin_amdgcn_mfma_f32_16x16x32_bf16(afrag, bfrag, a, 0, 0, 0);
        }
    }
    __syncthreads();   // all p5 frag reads drained; A_bf/xvT now dead

    // ---- write zA over dead A_bf/xvT region ----
    #pragma unroll
    for (int mt = 0; mt < 5; ++mt) {
        #pragma unroll
        for (int reg = 0; reg < 4; ++reg) {
            int r = 16 * mt + 4 * g + reg;
            if (r < 75) {
                int h = r / 25, i = r - h * 25;
                zA[i * 200 + h * 64 + 16 * w + l15] = f2bf(zacc[mt][reg]);
            }
        }
    }
    __syncthreads();

    // ---- phase 6: conv MFMA + BN + residual + ReLU -> res ----
    {
        float bg = bn_g[o], bv = bn_v[o], bb = bn_b[o], bm = bn_m[o];
        float cb = conv_b[o] + conv_b[64 + o] + conv_b[128 + o];

        const int r1 = (16 + l15 < 25) ? (16 + l15) : 0;
        f32x4 acc0 = {0.f, 0.f, 0.f, 0.f}, acc1 = {0.f, 0.f, 0.f, 0.f};
        #pragma unroll
        for (int kt = 0; kt < 6; ++kt) {
            bf16x8 a0 = *(bf16x8*)&zA[l15 * 200 + 32 * kt + 8 * g];
            bf16x8 a1 = *(bf16x8*)&zA[r1 * 200 + 32 * kt + 8 * g];
            acc0 = __builtin_amdgcn_mfma_f32_16x16x32_bf16(a0, cw[kt], acc0, 0, 0, 0);
            acc1 = __builtin_amdgcn_mfma_f32_16x16x32_bf16(a1, cw[kt], acc1, 0, 0, 0);
        }
        float sc = bg * rsqrtf(bv + 1e-5f);
        float bi = cb * sc + bb - bm * sc;
        #pragma unroll
        for (int reg = 0; reg < 4; ++reg) {
            int v = 4 * g + reg;
            float val = acc0[reg] * sc + bi + xv[v * 65 + o];
            res[o * 25 + v] = fmaxf(val, 0.f);
        }
        #pragma unroll
        for (int reg = 0; reg < 4; ++reg) {
            int v = 16 + 4 * g + reg;
            if (v < 25) {
                float val = acc1[reg] * sc + bi + xv[v * 65 + o];
                res[o * 25 + v] = fmaxf(val, 0.f);
            }
        }
    }
    __syncthreads();

    // ---- coalesced store ----
    {
        float* ob = out + (size_t)n * 204800 + t * 25;
        for (int idx = tid; idx < 1600; idx += 256) {
            int c = idx / 25, v = idx - c * 25;
            ob[c * 3200 + v] = res[idx];
        }
    }
}

extern "C" void kernel_launch(void* const* d_in, const int* in_sizes, int n_in,
                              void* d_out, int out_size, void* d_ws, size_t ws_size,
                              hipStream_t stream) {
    const float* x      = (const float*)d_in[0];
    const float* PA     = (const float*)d_in[1];
    const float* ln_g   = (const float*)d_in[2];
    const float* ln_b   = (const float*)d_in[3];
    const float* Wqk    = (const float*)d_in[4];
    const float* bqk    = (const float*)d_in[5];
    const float* conv_w = (const float*)d_in[6];
    const float* conv_b = (const float*)d_in[7];
    const float* bn_g   = (const float*)d_in[8];
    const float* bn_b   = (const float*)d_in[9];
    const float* bn_m   = (const float*)d_in[10];
    const float* bn_v   = (const float*)d_in[11];
    float* outp = (float*)d_out;

    agcn_fused_kernel<<<dim3(128 * 128), dim3(256), 0, stream>>>(
        x, PA, ln_g, ln_b, Wqk, bqk, conv_w, conv_b,
        bn_g, bn_b, bn_m, bn_v, outp);
}